// Round 15
// baseline (1620.293 us; speedup 1.0000x reference)
//
#include <hip/hip_runtime.h>

typedef _Float16 f16;
typedef _Float16 f16x8 __attribute__((ext_vector_type(8)));
typedef float f32x4 __attribute__((ext_vector_type(4)));
typedef unsigned short ushort_t;
typedef unsigned long long u64_t;

// ---------------------------------------------------------------------------
// PoseConvLSTM via implicit-GEMM MFMA. Multi-launch temporal-skew fusion.
//
// Round 15: 64-pixel tiles for the L2 role. r14 = 1541us; dominant body term
// is the per-step weight stream from L2 (75 MB/step), amortized over only
// 32 px/block. L2 retiled: 4 m-blocks x 64 tiles of 64 px (MT=4, MTPW=1,
// NT=4) -> per-block weight slice halves, L2 weight traffic 56.6 -> 28.3
// MB/step. LDS reads + MFMAs per pixel unchanged; A-ring 64->32 VGPRs
// (r13 spill lesson); grid stays 512 = 2 blocks/CU; LDS ~23.5 KB.
// The r11 direct-from-acc epilogue identity generalizes: for MT=4/MTPW=1,
// hg = mb*16 + w*4 + q, gate = reg (both layers). in2b concurrent writers
// now split each 128B pixel line 4-way in 32B sectors (2-way has passed
// since r9; 32B is the HW sector granule). Numerics bit-identical.
//
// Kernel K_t: blocks 0-255 = L1[t], blocks 256-511 = L2[t-1] (temporal skew,
// no intra-kernel dependency). All stores NORMAL (kernel-boundary coherence).
//   in1[parity]: [66][66][48]  h1prev c0-31, x[t] c32-34, 0 c35-47 (L1-writ)
//   in2b[parity]: [66][66][64] h2[t-1] (L2-written only)
// L2 reads h1[t-1] directly from in1[p] c0-31 (stride 48).
// Weights hi-only f16 (r10); fcwp[cidx*6+j] f32 (r9); direct-from-acc LSTM
// epilogue (r11); LDS-transposed 8B h-stores (r9); in2a eliminated (r14).
//
// d_out (floats): pose[768] | h1[131072] | c1[131072] | h2[262144] | c2[262144]
// ---------------------------------------------------------------------------

#define IN1SZ 209088    // 66*66*48
#define IN2BSZ 278784   // 66*66*64
#define WP1OFF 975744   // ushort offset of wp1 (2*IN1SZ + 2*IN2BSZ)
#define WP1SZ 73728     // 2mb*18s*4mt*512 (hi only)
#define WP2OFF (WP1OFF + WP1SZ)
#define WP2SZ 221184    // 4mb*27s*4mt*512 (hi only)
#define FCWPOFF (WP2OFF + WP2SZ)  // 1270656 ushorts -> 2541312 B (128B-mult)

__device__ __forceinline__ float sigm(float x) {
  return __builtin_amdgcn_rcpf(1.0f + __expf(-x));
}
__device__ __forceinline__ float tanh_fast(float x) {
  float xc = fminf(fmaxf(x, -10.f), 10.f);
  float e = __expf(2.f * xc);
  return (e - 1.f) * __builtin_amdgcn_rcpf(e + 1.f);
}
__device__ __forceinline__ ushort_t f2u(f16 v) { return __builtin_bit_cast(ushort_t, v); }
__device__ __forceinline__ f16x8 u2f(uint4 v) { return __builtin_bit_cast(f16x8, v); }

// ---- init: pack weights (hi-only, h1@c0 x@c32 order), fcw transpose, x[0] ----
__global__ __launch_bounds__(256) void pack_kernel(const float* __restrict__ w1,
                                                   const float* __restrict__ w2,
                                                   const float* __restrict__ fcb,
                                                   const float* __restrict__ x0,
                                                   const float* __restrict__ fcw,
                                                   float* __restrict__ pose,
                                                   ushort_t* __restrict__ wp1,
                                                   ushort_t* __restrict__ wp2,
                                                   ushort_t* __restrict__ in1hi0,
                                                   float* __restrict__ fcwp) {
  int i = blockIdx.x * 256 + threadIdx.x;
  if (i < 27648) {  // wp2: thread per (f, lane), 8 elems each. f=(mb*27+s)*4+mt
    int lane = i & 63;
    int f = i >> 6;         // [0, 432)
    int mt = f & 3;
    int sm = f >> 2;        // [0,108)
    int s = sm % 27, mb = sm / 27;  // mb in [0,4)
    int m = mt * 16 + (lane & 15);
    int rg = mb * 64 + m;
    int h = rg >> 2, G = rg & 3;
    int orow = G * 64 + h;
    int tap = s / 3, cb = (s % 3) * 32;
    int cq = cb + (lane >> 4) * 8;
    for (int j = 0; j < 8; ++j) {
      float v = w2[(orow * 96 + cq + j) * 9 + tap];
      wp2[f * 512 + lane * 8 + j] = f2u((f16)v);
    }
    return;
  }
  i -= 27648;
  if (i < 9216) {  // wp1 (channel order: c0-31 = h1 (ref 3+c), c32-34 = x)
    int lane = i & 63;
    int f = i >> 6;         // [0,144) = (mb*18+s)*4+mt
    int mt = f & 3;
    int sm = f >> 2;        // [0,36)
    int s = sm % 18, mb = sm / 18;
    int m = mt * 16 + (lane & 15);
    int rg = mb * 64 + m;
    int h = rg >> 2, G = rg & 3;
    int orow = G * 32 + h;
    int tap = s >> 1, cb = (s & 1) * 32;
    int cq = cb + (lane >> 4) * 8;
    for (int j = 0; j < 8; ++j) {
      int c = cq + j;
      float v = 0.f;
      if (c < 32) v = w1[(orow * 35 + c + 3) * 9 + tap];
      else if (c < 35) v = w1[(orow * 35 + c - 32) * 9 + tap];
      wp1[f * 512 + lane * 8 + j] = f2u((f16)v);
    }
    return;
  }
  i -= 9216;
  if (i < 768) { pose[i] = fcb[i % 6]; return; }
  i -= 768;
  if (i < 12288) {  // x[0] -> in1[0] c32-34
    int c = i >> 12, pix = i & 4095;
    int y = pix >> 6, x = pix & 63;
    int pidx = ((y + 1) * 66 + (x + 1)) * 48 + 32 + c;
    in1hi0[pidx] = f2u((f16)x0[i]);
    return;
  }
  i -= 12288;
  if (i < 262144) {  // fcw transpose: fcwp[cidx*6+j] = fcw[j*262144+cidx]
    float* dst = fcwp + (size_t)i * 6;
#pragma unroll
    for (int j = 0; j < 6; ++j) dst[j] = fcw[(size_t)j * 262144 + i];
  }
}

// ---- one ConvLSTM step for one layer (device body) ----
// block 256 = 4 waves; wave w = m-tile. MT=4, MTPW=1 both layers.
// L1: bid = mb(1b) | tile(7b): 2 mb x 128 tiles of 32 px (4y x 8x), NT=2.
// L2: bid = mb(2b) | tile(6b): 4 mb x  64 tiles of 64 px (8y x 8x), NT=4.
// L1: input = bhi (in1[p]: h1@c0-31, x@c32-34). Writes d1 = in1[pn].
// L2: input = bhi (in1[p] c0-31 = h1[t-1]) + b2hi (in2b[pn], 64ch).
//     Writes d1 = in2b[p].
template <int LAYER>
__device__ __forceinline__ void conv_body(
    int bid,
    const ushort_t* __restrict__ bhi, const ushort_t* __restrict__ b2hi,
    const ushort_t* __restrict__ wp, const float* __restrict__ bias,
    float* __restrict__ cst, float* __restrict__ hout,              // fp32 c (in-place), h
    ushort_t* __restrict__ d1hi,                                    // primary dest
    const float* __restrict__ fcwp, float* __restrict__ pose_t,     // L2 only
    const float* __restrict__ xn,                                   // L1 only: x[t+1]
    ushort_t* Bh, ushort_t* hs, float (*red)[6]) {
  constexpr int CS = (LAYER == 1) ? 72 : 104;   // LDS c-stride (bank-conflict pad)
  constexpr int NC32 = (LAYER == 1) ? 2 : 3;    // 32-channel chunks
  constexpr int NS = 9 * NC32;                  // k32 steps
  constexpr int MT = 4;                         // m-tiles per block (1 per wave)
  constexpr int H = (LAYER == 1) ? 32 : 64;
  constexpr int NT = (LAYER == 1) ? 2 : 4;      // 16-px sub-tiles
  constexpr int TY = (LAYER == 1) ? 4 : 8;      // tile height (x-width = 8)
  constexpr int MBB = (LAYER == 1) ? 1 : 2;     // m-block bits
  constexpr int DEPTH = 8;                      // A-frag register ring (hi only)
  constexpr int PRE = DEPTH - 1;

  const int tid = threadIdx.x;
  const int lane = tid & 63;
  const int w = tid >> 6;
  const int mb = bid & ((1 << MBB) - 1);
  const int ntile = bid >> MBB;
  const int Y0 = (ntile >> 3) * TY;
  const int X0 = (ntile & 7) * 8;

  // ---- stage halo slab [(TY+2)y][10x][C] into LDS (issued FIRST) ----
  if (LAYER == 2) {
    for (int i = tid; i < (TY + 2) * 10 * 12; i += 256) {
      int hy = i / 120, rem = i % 120;
      int hx = rem / 12, c8 = rem % 12;
      int pos = (Y0 + hy) * 66 + X0 + hx;
      int dst = (hy * 10 + hx) * CS + c8 * 8;
      if (c8 < 4) {  // c0-31 = h1[t-1] from in1[p] (stride 48)
        *(uint4*)(&Bh[dst]) = *(const uint4*)(&bhi[pos * 48 + c8 * 8]);
      } else {       // c32-95 = h2[t-2] from in2b[pn] (stride 64)
        *(uint4*)(&Bh[dst]) = *(const uint4*)(&b2hi[pos * 64 + (c8 - 4) * 8]);
      }
    }
  } else {
    for (int i = tid; i < 360; i += 256) {
      int hy = i / 60, rem = i % 60;
      int hx = rem / 6, c8 = (rem % 6) * 8;
      int src = ((Y0 + hy) * 66 + X0 + hx) * 48 + c8;
      int dst = (hy * 10 + hx) * CS + c8;
      *(uint4*)(&Bh[dst]) = *(const uint4*)(&bhi[src]);
    }
    for (int i = tid; i < 120; i += 256) {  // zero-pad c 48..63 (read by frags)
      int hp = i >> 1;
      int dst = hp * CS + 48 + (i & 1) * 8;
      *(uint4*)(&Bh[dst]) = uint4{0, 0, 0, 0};
    }
  }

  // ---- A-frag register ring (weight hi only, 1 m-tile per wave) ----
  const ushort_t* aptr = wp + ((mb * NS) * MT + w) * 512 + lane * 8;
  uint4 A[DEPTH];
  auto loada = [&](int s) {
    A[s % DEPTH] = *(const uint4*)(aptr + (size_t)s * (MT * 512));
  };
#pragma unroll
  for (int s = 0; s < PRE; ++s) loada(s);
  __syncthreads();

  // ---- K-loop: A frag from registers (ring-prefetched), B frags from LDS ----
  const int n = lane & 15;
  const int q = lane >> 4;
  const int py = n >> 3, px = n & 7;

  f32x4 acc[NT];
#pragma unroll
  for (int nt = 0; nt < NT; ++nt) acc[nt] = f32x4{0.f, 0.f, 0.f, 0.f};

#pragma unroll
  for (int s = 0; s < NS; ++s) {
    // rolling prefetch: writes ring slot consumed LAST iteration (WAR-bounded)
    if (s + PRE < NS) loada(s + PRE);
    const int tap = s / NC32, cc = s % NC32;
    const int ty = tap / 3, tx = tap % 3;
    const int coff = cc * 32 + q * 8;
    f16x8 ah = u2f(A[s % DEPTH]);
#pragma unroll
    for (int nt = 0; nt < NT; ++nt) {
      int hp = (py + nt * 2 + ty) * 10 + (px + tx);
      f16x8 bfh = u2f(*(const uint4*)(&Bh[hp * CS + coff]));
      acc[nt] = __builtin_amdgcn_mfma_f32_16x16x32_f16(ah, bfh, acc[nt], 0, 0, 0);
    }
  }

  // ---- LSTM cell DIRECTLY from acc (r11 identity, MT=4/MTPW=1 form):
  //      lane (n,q) of wave w holds gates i,f,o,g of cell
  //      (hg = mb*16 + w*4 + q, pixel = nt*16+n) in acc[nt][0..3] ----
  float p6[6] = {0, 0, 0, 0, 0, 0};
  const int ch = w * 4 + q;          // channel within this block (0..15)
  const int hg = mb * 16 + ch;       // global h-channel
  const float bi = bias[0 * H + hg];
  const float bf = bias[1 * H + hg];
  const float bo = bias[2 * H + hg];
  const float bg = bias[3 * H + hg];
#pragma unroll
  for (int nt = 0; nt < NT; ++nt) {
    const int pI = nt * 16 + n;
    float zi = acc[nt][0] + bi;
    float zf = acc[nt][1] + bf;
    float zo = acc[nt][2] + bo;
    float zg = acc[nt][3] + bg;
    int y = Y0 + (pI >> 3), x = X0 + (pI & 7);
    int cidx = hg * 4096 + y * 64 + x;
    float cold = cst[cidx];
    float cn = sigm(zf) * cold + sigm(zi) * tanh_fast(zg);
    float hn = sigm(zo) * tanh_fast(cn);
    cst[cidx] = cn;
    hout[cidx] = hn;
    hs[pI * 20 + ch] = f2u((f16)hn);
    if (LAYER == 2) {
#pragma unroll
      for (int j = 0; j < 6; ++j) p6[j] += hn * fcwp[(size_t)cidx * 6 + j];
    }
  }
  __syncthreads();  // hs complete

  // ---- coalesced h-staging stores (plain 8B stores, 32B sector granules) ----
  if (LAYER == 2) {
    int pxi = tid & 63, g = tid >> 6;   // 64 px x 4 ch-groups of 4
    int y = Y0 + (pxi >> 3), x = X0 + (pxi & 7);
    int pidx = (y + 1) * 66 + (x + 1);
    u64_t v = *(const u64_t*)&hs[pxi * 20 + g * 4];
    *(u64_t*)&d1hi[pidx * 64 + mb * 16 + g * 4] = v;   // in2b[p]: h2
  } else {
    if (tid < 128) {                    // 32 px x 4 ch-groups of 4
      int pxi = tid & 31, g = tid >> 5;
      int y = Y0 + (pxi >> 3), x = X0 + (pxi & 7);
      int pidx = (y + 1) * 66 + (x + 1);
      u64_t v = *(const u64_t*)&hs[pxi * 20 + g * 4];
      *(u64_t*)&d1hi[pidx * 48 + mb * 16 + g * 4] = v; // in1[pn]: h1 @c0
    }
    // stage x[t+1] into in1 next-parity (c32-34; granule c32-47 mb0-only)
    if (mb == 0 && tid >= 128 && tid < 160) {
      int t2 = tid - 128;
      int yy = Y0 + (t2 >> 3), xx = X0 + (t2 & 7);
      int pidx2 = (yy + 1) * 66 + (xx + 1);
#pragma unroll
      for (int c = 0; c < 3; ++c) {
        d1hi[pidx2 * 48 + 32 + c] = f2u((f16)xn[c * 4096 + yy * 64 + xx]);
      }
    }
  }

  if (LAYER == 2) {
#pragma unroll
    for (int j = 0; j < 6; ++j)
#pragma unroll
      for (int off = 32; off > 0; off >>= 1) p6[j] += __shfl_xor(p6[j], off, 64);
    if (lane == 0)
#pragma unroll
      for (int j = 0; j < 6; ++j) red[w][j] = p6[j];
    __syncthreads();
    if (tid < 6) atomicAdd(pose_t + tid, red[0][tid] + red[1][tid] + red[2][tid] + red[3][tid]);
  }
}

// ---- fused temporal-skew kernel: blocks 0-255 = L1[t], 256-511 = L2[t-1] ----
__global__ __launch_bounds__(256, 2) void fused_step(
    int t,
    const ushort_t* __restrict__ i1rhi, ushort_t* __restrict__ i1whi,
    const ushort_t* __restrict__ i2brhi, ushort_t* __restrict__ i2bwhi,
    const ushort_t* __restrict__ wp1, const ushort_t* __restrict__ wp2,
    const float* __restrict__ b1, const float* __restrict__ b2,
    float* __restrict__ c1o, float* __restrict__ h1o,
    float* __restrict__ c2o, float* __restrict__ h2o,
    const float* __restrict__ fcwp, float* __restrict__ pose_t,
    const float* __restrict__ xn) {
  // union'd shared memory: max over both roles (L2 sizes), ~23.5 KB
  __shared__ __align__(16) ushort_t Bh[10400];  // max(60*72, 100*104)
  __shared__ __align__(8) ushort_t hs[1280];    // max(32,64)px * 20-stride
  __shared__ float red[4][6];

  int bid = blockIdx.x;
  if (bid < 256) {
    if (t >= 128) return;
    conv_body<1>(bid, i1rhi, nullptr, wp1, b1, c1o, h1o,
                 i1whi,                 // h1 -> in1[pn] @c0 (+ x[t+1] @c32)
                 nullptr, nullptr, xn, Bh, hs, red);
  } else {
    if (t < 1) return;
    conv_body<2>(bid - 256, i1rhi, i2brhi, wp2, b2, c2o, h2o,
                 i2bwhi,                // h2 -> in2b[p]
                 fcwp, pose_t, nullptr, Bh, hs, red);
  }
}

extern "C" void kernel_launch(void* const* d_in, const int* in_sizes, int n_in, void* d_out,
                              int out_size, void* d_ws, size_t ws_size, hipStream_t stream) {
  const float* input = (const float*)d_in[0];
  const float* w1 = (const float*)d_in[1];
  const float* b1 = (const float*)d_in[2];
  const float* w2 = (const float*)d_in[3];
  const float* b2 = (const float*)d_in[4];
  const float* fcw = (const float*)d_in[5];
  const float* fcb = (const float*)d_in[6];

  float* out = (float*)d_out;
  float* pose = out;
  float* h1o = out + 768;
  float* c1o = h1o + 131072;
  float* h2o = c1o + 131072;
  float* c2o = h2o + 262144;

  ushort_t* ws = (ushort_t*)d_ws;
  ushort_t* in1hi[2] = {ws, ws + IN1SZ};
  ushort_t* bb = ws + 2 * IN1SZ;
  ushort_t* i2bhi[2] = {bb, bb + IN2BSZ};
  ushort_t* wp1 = ws + WP1OFF;
  ushort_t* wp2 = ws + WP2OFF;
  float* fcwp = (float*)(ws + FCWPOFF);  // 6.29 MB

  // zero state buffers (t=0 h-states + padded borders). Output region: only
  // c-states need zero (h fully overwritten every step): c1|h2|c2 span.
  hipMemsetAsync(ws, 0, (size_t)WP1OFF * 2, stream);
  hipMemsetAsync(c1o, 0, (size_t)655360 * 4, stream);
  pack_kernel<<<1219, 256, 0, stream>>>(w1, w2, fcb, input, fcw, pose, wp1, wp2,
                                        in1hi[0], fcwp);

  // K_t: L1[t] (t<128) + L2[t-1] (t>=1).
  //   L1[t]: reads in1[p]; writes in1[pn] (h1[t]@c0 + x[t+1]@c32).
  //   L2[t-1]: reads in1[p] c0-31 (h1[t-1]) + in2b[pn] (h2[t-2]); writes in2b[p].
  for (int t = 0; t <= 128; ++t) {
    int p = t & 1, pn = p ^ 1;
    int tn = (t + 1 < 128) ? t + 1 : 127;
    float* pose_t = pose + ((t > 0) ? (t - 1) * 6 : 0);
    fused_step<<<512, 256, 0, stream>>>(
        t,
        in1hi[p], in1hi[pn],
        i2bhi[pn], i2bhi[p],
        wp1, wp2, b1, b2, c1o, h1o, c2o, h2o,
        fcwp, pose_t,
        input + (size_t)tn * 12288);
  }
}

// Round 16
// 1521.855 us; speedup vs baseline: 1.0647x; 1.0647x over previous
//
#include <hip/hip_runtime.h>

typedef _Float16 f16;
typedef _Float16 f16x8 __attribute__((ext_vector_type(8)));
typedef float f32x4 __attribute__((ext_vector_type(4)));
typedef unsigned short ushort_t;
typedef unsigned long long u64_t;

// ---------------------------------------------------------------------------
// PoseConvLSTM via implicit-GEMM MFMA. Multi-launch temporal-skew fusion.
//
// Round 16 = FINAL: exact revert to round 14 (best verified: 1541 us,
// absmax 0.0156 vs threshold 0.0631). r15's 64px-L2-retile regressed (+5%:
// halo staging critical path grew 67%; weights were already L2-amortized
// across same-mb blocks per XCD). r13's epilogue prefetch regressed (+8%:
// VGPR spills under launch_bounds(256,2)). r5-r8/r12 proved software grid
// publishes (cooperative, agent atomics, fence barriers) are strictly worse
// than kernel-boundary coherence on non-coherent XCDs.
//
// Final structure: 129 launches of fused_step (temporal skew: blocks 0-255 =
// L1[t], 256-511 = L2[t-1]; no intra-kernel dependency).
//   in1[parity]: [66][66][48]  h1prev c0-31, x[t] c32-34, 0 c35-47 (L1-writ)
//   in2b[parity]: [66][66][64] h2[t-1] (L2-written only)
// L2 reads h1[t-1] directly from in1[p] c0-31 (stride 48); in2a eliminated.
// Weights hi-only f16, fragment-packed, 8-deep register ring; fcwp[cidx*6+j]
// f32 transpose-pack; direct-from-acc LSTM epilogue (MFMA C/D layout holds
// all 4 gates of one cell per lane); LDS-transposed 8B h-stores; concurrent
// writers own disjoint 32B granules; all stores normal (kernel-boundary
// coherence).
//
// d_out (floats): pose[768] | h1[131072] | c1[131072] | h2[262144] | c2[262144]
// ---------------------------------------------------------------------------

#define IN1SZ 209088    // 66*66*48
#define IN2BSZ 278784   // 66*66*64
#define WP1OFF 975744   // ushort offset of wp1 (2*IN1SZ + 2*IN2BSZ)
#define WP1SZ 73728     // 2mb*18s*4mt*512 (hi only)
#define WP2OFF (WP1OFF + WP1SZ)
#define WP2SZ 221184    // 2mb*27s*8mt*512 (hi only)
#define FCWPOFF (WP2OFF + WP2SZ)  // 1270656 ushorts -> 2541312 B (128B-mult)

__device__ __forceinline__ float sigm(float x) {
  return __builtin_amdgcn_rcpf(1.0f + __expf(-x));
}
__device__ __forceinline__ float tanh_fast(float x) {
  float xc = fminf(fmaxf(x, -10.f), 10.f);
  float e = __expf(2.f * xc);
  return (e - 1.f) * __builtin_amdgcn_rcpf(e + 1.f);
}
__device__ __forceinline__ ushort_t f2u(f16 v) { return __builtin_bit_cast(ushort_t, v); }
__device__ __forceinline__ f16x8 u2f(uint4 v) { return __builtin_bit_cast(f16x8, v); }

// ---- init: pack weights (hi-only, h1@c0 x@c32 order), fcw transpose, x[0] ----
__global__ __launch_bounds__(256) void pack_kernel(const float* __restrict__ w1,
                                                   const float* __restrict__ w2,
                                                   const float* __restrict__ fcb,
                                                   const float* __restrict__ x0,
                                                   const float* __restrict__ fcw,
                                                   float* __restrict__ pose,
                                                   ushort_t* __restrict__ wp1,
                                                   ushort_t* __restrict__ wp2,
                                                   ushort_t* __restrict__ in1hi0,
                                                   float* __restrict__ fcwp) {
  int i = blockIdx.x * 256 + threadIdx.x;
  if (i < 27648) {  // wp2: thread per (f, lane), 8 elems each
    int lane = i & 63;
    int f = i >> 6;         // [0, 432) = (mb*27+s)*8+mt
    int mt = f & 7;
    int sm = f >> 3;        // [0,54)
    int s = sm % 27, mb = sm / 27;
    int m = mt * 16 + (lane & 15);
    int rg = mb * 128 + m;
    int h = rg >> 2, G = rg & 3;
    int orow = G * 64 + h;
    int tap = s / 3, cb = (s % 3) * 32;
    int cq = cb + (lane >> 4) * 8;
    for (int j = 0; j < 8; ++j) {
      float v = w2[(orow * 96 + cq + j) * 9 + tap];
      wp2[f * 512 + lane * 8 + j] = f2u((f16)v);
    }
    return;
  }
  i -= 27648;
  if (i < 9216) {  // wp1 (channel order: c0-31 = h1 (ref 3+c), c32-34 = x)
    int lane = i & 63;
    int f = i >> 6;         // [0,144) = (mb*18+s)*4+mt
    int mt = f & 3;
    int sm = f >> 2;        // [0,36)
    int s = sm % 18, mb = sm / 18;
    int m = mt * 16 + (lane & 15);
    int rg = mb * 64 + m;
    int h = rg >> 2, G = rg & 3;
    int orow = G * 32 + h;
    int tap = s >> 1, cb = (s & 1) * 32;
    int cq = cb + (lane >> 4) * 8;
    for (int j = 0; j < 8; ++j) {
      int c = cq + j;
      float v = 0.f;
      if (c < 32) v = w1[(orow * 35 + c + 3) * 9 + tap];
      else if (c < 35) v = w1[(orow * 35 + c - 32) * 9 + tap];
      wp1[f * 512 + lane * 8 + j] = f2u((f16)v);
    }
    return;
  }
  i -= 9216;
  if (i < 768) { pose[i] = fcb[i % 6]; return; }
  i -= 768;
  if (i < 12288) {  // x[0] -> in1[0] c32-34
    int c = i >> 12, pix = i & 4095;
    int y = pix >> 6, x = pix & 63;
    int pidx = ((y + 1) * 66 + (x + 1)) * 48 + 32 + c;
    in1hi0[pidx] = f2u((f16)x0[i]);
    return;
  }
  i -= 12288;
  if (i < 262144) {  // fcw transpose: fcwp[cidx*6+j] = fcw[j*262144+cidx]
    float* dst = fcwp + (size_t)i * 6;
#pragma unroll
    for (int j = 0; j < 6; ++j) dst[j] = fcw[(size_t)j * 262144 + i];
  }
}

// ---- one ConvLSTM step for one layer (device body) ----
// bid in [0,256) = 2 M-blocks x 128 pixel tiles (4y x 8x); block 256 = 4 waves.
// L1: input = bhi (in1[p]: h1@c0-31, x@c32-34). Writes d1 = in1[pn].
// L2: input = bhi (in1[p] c0-31 = h1[t-1]) + b2hi (in2b[pn], 64ch).
//     Writes d1 = in2b[p].
template <int LAYER>
__device__ __forceinline__ void conv_body(
    int bid,
    const ushort_t* __restrict__ bhi, const ushort_t* __restrict__ b2hi,
    const ushort_t* __restrict__ wp, const float* __restrict__ bias,
    float* __restrict__ cst, float* __restrict__ hout,              // fp32 c (in-place), h
    ushort_t* __restrict__ d1hi,                                    // primary dest
    const float* __restrict__ fcwp, float* __restrict__ pose_t,     // L2 only
    const float* __restrict__ xn,                                   // L1 only: x[t+1]
    ushort_t* Bh, ushort_t* hs, float (*red)[6]) {
  constexpr int CS = (LAYER == 1) ? 72 : 104;   // LDS c-stride (bank-conflict pad)
  constexpr int NC32 = (LAYER == 1) ? 2 : 3;    // 32-channel chunks
  constexpr int NS = 9 * NC32;                  // k32 steps
  constexpr int MT = (LAYER == 1) ? 4 : 8;      // 16-row m-tiles per block
  constexpr int MTPW = (LAYER == 1) ? 1 : 2;    // m-tiles per wave
  constexpr int H = (LAYER == 1) ? 32 : 64;
  constexpr int DEPTH = 8;                      // A-frag register ring (hi only)
  constexpr int PRE = DEPTH - 1;

  const int tid = threadIdx.x;
  const int lane = tid & 63;
  const int w = tid >> 6;
  const int mb = bid & 1;
  const int ntile = bid >> 1;
  const int Y0 = (ntile >> 3) * 4;
  const int X0 = (ntile & 7) * 8;

  // ---- stage halo slab [6y][10x][C] into LDS (issued FIRST) ----
  if (LAYER == 2) {
    for (int i = tid; i < 720; i += 256) {
      int hy = i / 120, rem = i % 120;
      int hx = rem / 12, c8 = rem % 12;
      int pos = (Y0 + hy) * 66 + X0 + hx;
      int dst = (hy * 10 + hx) * CS + c8 * 8;
      if (c8 < 4) {  // c0-31 = h1[t-1] from in1[p] (stride 48)
        *(uint4*)(&Bh[dst]) = *(const uint4*)(&bhi[pos * 48 + c8 * 8]);
      } else {       // c32-95 = h2[t-2] from in2b[pn] (stride 64)
        *(uint4*)(&Bh[dst]) = *(const uint4*)(&b2hi[pos * 64 + (c8 - 4) * 8]);
      }
    }
  } else {
    for (int i = tid; i < 360; i += 256) {
      int hy = i / 60, rem = i % 60;
      int hx = rem / 6, c8 = (rem % 6) * 8;
      int src = ((Y0 + hy) * 66 + X0 + hx) * 48 + c8;
      int dst = (hy * 10 + hx) * CS + c8;
      *(uint4*)(&Bh[dst]) = *(const uint4*)(&bhi[src]);
    }
    for (int i = tid; i < 120; i += 256) {  // zero-pad c 48..63 (read by frags)
      int hp = i >> 1;
      int dst = hp * CS + 48 + (i & 1) * 8;
      *(uint4*)(&Bh[dst]) = uint4{0, 0, 0, 0};
    }
  }

  // ---- A-frag register ring (weight hi only) ----
  const ushort_t* aptr[MTPW];
#pragma unroll
  for (int m = 0; m < MTPW; ++m) {
    int f = (mb * NS) * MT + (w * MTPW + m);
    aptr[m] = wp + f * 512 + lane * 8;
  }
  uint4 A[DEPTH][MTPW];
  auto loada = [&](int s) {
#pragma unroll
    for (int m = 0; m < MTPW; ++m) {
      A[s % DEPTH][m] = *(const uint4*)(aptr[m] + (size_t)s * (MT * 512));
    }
  };
#pragma unroll
  for (int s = 0; s < PRE; ++s) loada(s);
  __syncthreads();

  // ---- K-loop: A frags from registers (ring-prefetched), B frags from LDS ----
  const int n = lane & 15;
  const int q = lane >> 4;
  const int py = n >> 3, px = n & 7;

  f32x4 acc[MTPW][2];
#pragma unroll
  for (int m = 0; m < MTPW; ++m)
#pragma unroll
    for (int nt = 0; nt < 2; ++nt) acc[m][nt] = f32x4{0.f, 0.f, 0.f, 0.f};

#pragma unroll
  for (int s = 0; s < NS; ++s) {
    // rolling prefetch: writes ring slot consumed LAST iteration (WAR-bounded)
    if (s + PRE < NS) loada(s + PRE);
    const int tap = s / NC32, cc = s % NC32;
    const int ty = tap / 3, tx = tap % 3;
    const int coff = cc * 32 + q * 8;
    f16x8 bfh[2];
#pragma unroll
    for (int nt = 0; nt < 2; ++nt) {
      int hp = (py + nt * 2 + ty) * 10 + (px + tx);
      bfh[nt] = u2f(*(const uint4*)(&Bh[hp * CS + coff]));
    }
#pragma unroll
    for (int m = 0; m < MTPW; ++m) {
      f16x8 ah = u2f(A[s % DEPTH][m]);
#pragma unroll
      for (int nt = 0; nt < 2; ++nt) {
        acc[m][nt] = __builtin_amdgcn_mfma_f32_16x16x32_f16(ah, bfh[nt], acc[m][nt], 0, 0, 0);
      }
    }
  }

  // ---- LSTM cell DIRECTLY from acc: lane (n,q) of m-tile mt holds gates
  //      i,f,o,g of cell (ch=mt*4+q, pixel=nt*16+n) in acc[m][nt][0..3] ----
  float p6[6] = {0, 0, 0, 0, 0, 0};
#pragma unroll
  for (int m = 0; m < MTPW; ++m) {
    const int ch = (w * MTPW + m) * 4 + q;   // channel within mb half
    const int hg = mb * (MT * 4) + ch;
    const float bi = bias[0 * H + hg];
    const float bf = bias[1 * H + hg];
    const float bo = bias[2 * H + hg];
    const float bg = bias[3 * H + hg];
#pragma unroll
    for (int nt = 0; nt < 2; ++nt) {
      const int pI = nt * 16 + n;
      float zi = acc[m][nt][0] + bi;
      float zf = acc[m][nt][1] + bf;
      float zo = acc[m][nt][2] + bo;
      float zg = acc[m][nt][3] + bg;
      int y = Y0 + (pI >> 3), x = X0 + (pI & 7);
      int cidx = hg * 4096 + y * 64 + x;
      float cold = cst[cidx];
      float cn = sigm(zf) * cold + sigm(zi) * tanh_fast(zg);
      float hn = sigm(zo) * tanh_fast(cn);
      cst[cidx] = cn;
      hout[cidx] = hn;
      hs[pI * 36 + ch] = f2u((f16)hn);
      if (LAYER == 2) {
#pragma unroll
        for (int j = 0; j < 6; ++j) p6[j] += hn * fcwp[(size_t)cidx * 6 + j];
      }
    }
  }
  __syncthreads();  // hs complete

  // ---- coalesced h-staging stores (plain 8B stores, full 32B granules) ----
  if (LAYER == 2) {
    int pxi = tid & 31, g = tid >> 5;   // 32 px x 8 ch-groups of 4
    int y = Y0 + (pxi >> 3), x = X0 + (pxi & 7);
    int pidx = (y + 1) * 66 + (x + 1);
    u64_t v = *(const u64_t*)&hs[pxi * 36 + g * 4];
    *(u64_t*)&d1hi[pidx * 64 + mb * 32 + g * 4] = v;   // in2b[p]: h2
  } else {
    if (tid < 128) {                    // 32 px x 4 ch-groups of 4
      int pxi = tid & 31, g = tid >> 5;
      int y = Y0 + (pxi >> 3), x = X0 + (pxi & 7);
      int pidx = (y + 1) * 66 + (x + 1);
      u64_t v = *(const u64_t*)&hs[pxi * 36 + g * 4];
      *(u64_t*)&d1hi[pidx * 48 + mb * 16 + g * 4] = v; // in1[pn]: h1 @c0
    }
    // stage x[t+1] into in1 next-parity (c32-34; granule c32-47 mb0-only)
    if (mb == 0 && tid >= 128 && tid < 160) {
      int t2 = tid - 128;
      int yy = Y0 + (t2 >> 3), xx = X0 + (t2 & 7);
      int pidx2 = (yy + 1) * 66 + (xx + 1);
#pragma unroll
      for (int c = 0; c < 3; ++c) {
        d1hi[pidx2 * 48 + 32 + c] = f2u((f16)xn[c * 4096 + yy * 64 + xx]);
      }
    }
  }

  if (LAYER == 2) {
#pragma unroll
    for (int j = 0; j < 6; ++j)
#pragma unroll
      for (int off = 32; off > 0; off >>= 1) p6[j] += __shfl_xor(p6[j], off, 64);
    if (lane == 0)
#pragma unroll
      for (int j = 0; j < 6; ++j) red[w][j] = p6[j];
    __syncthreads();
    if (tid < 6) atomicAdd(pose_t + tid, red[0][tid] + red[1][tid] + red[2][tid] + red[3][tid]);
  }
}

// ---- fused temporal-skew kernel: blocks 0-255 = L1[t], 256-511 = L2[t-1] ----
__global__ __launch_bounds__(256, 2) void fused_step(
    int t,
    const ushort_t* __restrict__ i1rhi, ushort_t* __restrict__ i1whi,
    const ushort_t* __restrict__ i2brhi, ushort_t* __restrict__ i2bwhi,
    const ushort_t* __restrict__ wp1, const ushort_t* __restrict__ wp2,
    const float* __restrict__ b1, const float* __restrict__ b2,
    float* __restrict__ c1o, float* __restrict__ h1o,
    float* __restrict__ c2o, float* __restrict__ h2o,
    const float* __restrict__ fcwp, float* __restrict__ pose_t,
    const float* __restrict__ xn) {
  // union'd shared memory: max over both roles (L2 sizes), ~15 KB
  __shared__ __align__(16) ushort_t Bh[6240];   // max(60*72, 60*104)
  __shared__ __align__(8) ushort_t hs[1152];    // 32px * 36-stride hh stage
  __shared__ float red[4][6];

  int bid = blockIdx.x;
  if (bid < 256) {
    if (t >= 128) return;
    conv_body<1>(bid, i1rhi, nullptr, wp1, b1, c1o, h1o,
                 i1whi,                 // h1 -> in1[pn] @c0 (+ x[t+1] @c32)
                 nullptr, nullptr, xn, Bh, hs, red);
  } else {
    if (t < 1) return;
    conv_body<2>(bid - 256, i1rhi, i2brhi, wp2, b2, c2o, h2o,
                 i2bwhi,                // h2 -> in2b[p]
                 fcwp, pose_t, nullptr, Bh, hs, red);
  }
}

extern "C" void kernel_launch(void* const* d_in, const int* in_sizes, int n_in, void* d_out,
                              int out_size, void* d_ws, size_t ws_size, hipStream_t stream) {
  const float* input = (const float*)d_in[0];
  const float* w1 = (const float*)d_in[1];
  const float* b1 = (const float*)d_in[2];
  const float* w2 = (const float*)d_in[3];
  const float* b2 = (const float*)d_in[4];
  const float* fcw = (const float*)d_in[5];
  const float* fcb = (const float*)d_in[6];

  float* out = (float*)d_out;
  float* pose = out;
  float* h1o = out + 768;
  float* c1o = h1o + 131072;
  float* h2o = c1o + 131072;
  float* c2o = h2o + 262144;

  ushort_t* ws = (ushort_t*)d_ws;
  ushort_t* in1hi[2] = {ws, ws + IN1SZ};
  ushort_t* bb = ws + 2 * IN1SZ;
  ushort_t* i2bhi[2] = {bb, bb + IN2BSZ};
  ushort_t* wp1 = ws + WP1OFF;
  ushort_t* wp2 = ws + WP2OFF;
  float* fcwp = (float*)(ws + FCWPOFF);  // 6.29 MB

  // zero state buffers (t=0 h-states + padded borders). Output region: only
  // c-states need zero (h fully overwritten every step): c1|h2|c2 span.
  hipMemsetAsync(ws, 0, (size_t)WP1OFF * 2, stream);
  hipMemsetAsync(c1o, 0, (size_t)655360 * 4, stream);
  pack_kernel<<<1219, 256, 0, stream>>>(w1, w2, fcb, input, fcw, pose, wp1, wp2,
                                        in1hi[0], fcwp);

  // K_t: L1[t] (t<128) + L2[t-1] (t>=1).
  //   L1[t]: reads in1[p]; writes in1[pn] (h1[t]@c0 + x[t+1]@c32).
  //   L2[t-1]: reads in1[p] c0-31 (h1[t-1]) + in2b[pn] (h2[t-2]); writes in2b[p].
  for (int t = 0; t <= 128; ++t) {
    int p = t & 1, pn = p ^ 1;
    int tn = (t + 1 < 128) ? t + 1 : 127;
    float* pose_t = pose + ((t > 0) ? (t - 1) * 6 : 0);
    fused_step<<<512, 256, 0, stream>>>(
        t,
        in1hi[p], in1hi[pn],
        i2bhi[pn], i2bhi[p],
        wp1, wp2, b1, b2, c1o, h1o, c2o, h2o,
        fcwp, pose_t,
        input + (size_t)tn * 12288);
  }
}